// Round 1
// baseline (1727.804 us; speedup 1.0000x reference)
//
#include <hip/hip_runtime.h>
#include <hip/hip_bf16.h>

#define SLOPE 0.2f

// ---------------- CSR build ----------------

__global__ __launch_bounds__(256) void k_init(int* deg, int* cnt, int n) {
    int i = blockIdx.x * 256 + threadIdx.x;
    if (i < n) { deg[i] = 1; cnt[i] = 0; }   // deg starts at 1: self-loop
}

__global__ __launch_bounds__(256) void k_hist(const int* __restrict__ dstv, int* deg, int E) {
    int i = blockIdx.x * 256 + threadIdx.x;
    if (i < E) atomicAdd(&deg[dstv[i]], 1);
}

// exclusive scan of 1024-element chunks; block totals to bsums
__global__ __launch_bounds__(256) void k_scan(const int* __restrict__ in, int* __restrict__ out,
                                              int* bsums, int n) {
    __shared__ int wsum[4];
    int t = threadIdx.x;
    int base = blockIdx.x * 1024 + t * 4;
    int v0 = (base + 0 < n) ? in[base + 0] : 0;
    int v1 = (base + 1 < n) ? in[base + 1] : 0;
    int v2 = (base + 2 < n) ? in[base + 2] : 0;
    int v3 = (base + 3 < n) ? in[base + 3] : 0;
    int tsum = v0 + v1 + v2 + v3;
    int lane = t & 63, wid = t >> 6;
    int x = tsum;
    #pragma unroll
    for (int d = 1; d < 64; d <<= 1) {
        int y = __shfl_up(x, d);
        if (lane >= d) x += y;
    }
    if (lane == 63) wsum[wid] = x;
    __syncthreads();
    if (t == 0) {
        int a = 0;
        for (int w = 0; w < 4; ++w) { int b = wsum[w]; wsum[w] = a; a += b; }
    }
    __syncthreads();
    int excl = x - tsum + wsum[wid];
    if (base + 0 < n) out[base + 0] = excl;
    if (base + 1 < n) out[base + 1] = excl + v0;
    if (base + 2 < n) out[base + 2] = excl + v0 + v1;
    if (base + 3 < n) out[base + 3] = excl + v0 + v1 + v2;
    if (bsums != nullptr && t == 255) bsums[blockIdx.x] = excl + tsum;
}

__global__ __launch_bounds__(256) void k_scan_add(const int* __restrict__ dscan,
                                                  const int* __restrict__ boff,
                                                  int* __restrict__ rowptr, int n, int total) {
    int i = blockIdx.x * 256 + threadIdx.x;
    if (i < n) rowptr[i] = dscan[i] + boff[i >> 10];
    if (i == n) rowptr[n] = total;
}

__global__ __launch_bounds__(256) void k_fill(const int* __restrict__ srcv, const int* __restrict__ dstv,
                                              const int* __restrict__ rowptr, int* cnt, int* col,
                                              int E, int n) {
    int i = blockIdx.x * 256 + threadIdx.x;
    if (i < E) {
        int d = dstv[i];
        int pos = rowptr[d] + atomicAdd(&cnt[d], 1);
        col[pos] = srcv[i];
    } else if (i < E + n) {
        int d = i - E;
        int pos = rowptr[d] + atomicAdd(&cnt[d], 1);
        col[pos] = d;
    }
}

// ---------------- fp32 GEMM: Y = X(nrows x 128) @ W(128 x 128) ----------------
// blockIdx.y selects (W0->Y0) or (W1->Y1). 128x128 tile, 256 thr, 8x8 per thread.

__global__ __launch_bounds__(256) void k_gemm(const float* __restrict__ X,
                                              const float* __restrict__ W0,
                                              const float* __restrict__ W1,
                                              float* __restrict__ Y0, float* __restrict__ Y1,
                                              int nrows) {
    const float* __restrict__ W = blockIdx.y ? W1 : W0;
    float* __restrict__ Y = blockIdx.y ? Y1 : Y0;
    __shared__ float Xs[16][132];   // [k][row], pad 4 keeps float4 align, no read conflicts
    __shared__ float Ws[16][132];   // [k][col]
    int row0 = blockIdx.x * 128;
    int t = threadIdx.x;
    int tx = t & 15, ty = t >> 4;
    float acc[8][8];
    #pragma unroll
    for (int i = 0; i < 8; ++i)
        #pragma unroll
        for (int j = 0; j < 8; ++j) acc[i][j] = 0.f;

    for (int k0 = 0; k0 < 128; k0 += 16) {
        {
            int r = t >> 2;            // 0..63
            int kq = (t & 3) * 4;      // 0,4,8,12
            #pragma unroll
            for (int rr = 0; rr < 2; ++rr) {
                int row = row0 + r + rr * 64;
                float4 xv = (row < nrows) ? *(const float4*)&X[(size_t)row * 128 + k0 + kq]
                                          : make_float4(0.f, 0.f, 0.f, 0.f);
                Xs[kq + 0][r + rr * 64] = xv.x;
                Xs[kq + 1][r + rr * 64] = xv.y;
                Xs[kq + 2][r + rr * 64] = xv.z;
                Xs[kq + 3][r + rr * 64] = xv.w;
            }
        }
        {
            int kk = t >> 5;           // 0..7
            int c4 = (t & 31) * 4;
            #pragma unroll
            for (int rr = 0; rr < 2; ++rr) {
                int k = kk + rr * 8;
                *(float4*)&Ws[k][c4] = *(const float4*)&W[(size_t)(k0 + k) * 128 + c4];
            }
        }
        __syncthreads();
        #pragma unroll
        for (int k = 0; k < 16; ++k) {
            float a[8], b[8];
            *(float4*)&a[0] = *(const float4*)&Xs[k][ty * 8];
            *(float4*)&a[4] = *(const float4*)&Xs[k][ty * 8 + 4];
            *(float4*)&b[0] = *(const float4*)&Ws[k][tx * 8];
            *(float4*)&b[4] = *(const float4*)&Ws[k][tx * 8 + 4];
            #pragma unroll
            for (int i = 0; i < 8; ++i)
                #pragma unroll
                for (int j = 0; j < 8; ++j) acc[i][j] = fmaf(a[i], b[j], acc[i][j]);
        }
        __syncthreads();
    }
    #pragma unroll
    for (int i = 0; i < 8; ++i) {
        int row = row0 + ty * 8 + i;
        if (row < nrows) {
            *(float4*)&Y[(size_t)row * 128 + tx * 8]     = *(float4*)&acc[i][0];
            *(float4*)&Y[(size_t)row * 128 + tx * 8 + 4] = *(float4*)&acc[i][4];
        }
    }
}

// ---------------- pass A: per-dst attention logits + online softmax stats ----------------
// One wave per dst. lane owns channels c=2*lane, 2*lane+1 (head = lane>>4).

__global__ __launch_bounds__(256) void pass_a(const float* __restrict__ XL,
                                              const float* __restrict__ XR,
                                              const float* __restrict__ att,
                                              const int* __restrict__ rowptr,
                                              const int* __restrict__ col,
                                              float* __restrict__ EXA,
                                              float* __restrict__ M, float* __restrict__ DEN,
                                              int n) {
    int wave = (blockIdx.x * blockDim.x + threadIdx.x) >> 6;
    int lane = threadIdx.x & 63;
    if (wave >= n) return;
    int dst = wave;
    int start = rowptr[dst], end = rowptr[dst + 1];
    int c = lane * 2;
    float2 xr = *(const float2*)&XR[(size_t)dst * 128 + c];
    float2 av = *(const float2*)&att[c];
    float m = -3.0e38f, s = 0.f;
    for (int p = start; p < end; ++p) {
        int src = col[p];
        float2 xl = *(const float2*)&XL[(size_t)src * 128 + c];
        float v0 = xl.x + xr.x, v1 = xl.y + xr.y;
        v0 = (v0 > 0.f) ? v0 : v0 * SLOPE;
        v1 = (v1 > 0.f) ? v1 : v1 * SLOPE;
        float t = v0 * av.x + v1 * av.y;
        #pragma unroll
        for (int d = 1; d < 16; d <<= 1) t += __shfl_xor(t, d);
        // all 16 lanes of this head-group now hold the logit
        if ((lane & 15) == 0) EXA[(size_t)p * 4 + (lane >> 4)] = t;
        if (t > m) { s = s * __expf(m - t) + 1.0f; m = t; }
        else       { s += __expf(t - m); }
    }
    if ((lane & 15) == 0) {
        int h = lane >> 4;
        M[dst * 4 + h] = m;
        DEN[dst * 4 + h] = s;
    }
}

// ---------------- pass B: weighted aggregation, fused bias+ReLU ----------------

__global__ __launch_bounds__(256) void pass_b_cat(const float* __restrict__ XL,
                                                  const float* __restrict__ EXA,
                                                  const float* __restrict__ M,
                                                  const float* __restrict__ DEN,
                                                  const float* __restrict__ bias,
                                                  const int* __restrict__ rowptr,
                                                  const int* __restrict__ col,
                                                  float* __restrict__ OUT, int n) {
    int wave = (blockIdx.x * blockDim.x + threadIdx.x) >> 6;
    int lane = threadIdx.x & 63;
    if (wave >= n) return;
    int dst = wave;
    int h = lane >> 4;
    float mh = M[dst * 4 + h];
    float rden = 1.0f / DEN[dst * 4 + h];
    int start = rowptr[dst], end = rowptr[dst + 1];
    float ax = 0.f, ay = 0.f;
    int c = lane * 2;
    for (int p = start; p < end; ++p) {
        int src = col[p];
        float lg = EXA[(size_t)p * 4 + h];
        float al = __expf(lg - mh) * rden;
        float2 xl = *(const float2*)&XL[(size_t)src * 128 + c];
        ax = fmaf(al, xl.x, ax);
        ay = fmaf(al, xl.y, ay);
    }
    float o0 = fmaxf(ax + bias[c], 0.f);
    float o1 = fmaxf(ay + bias[c + 1], 0.f);
    float2 o = make_float2(o0, o1);
    *(float2*)&OUT[(size_t)dst * 128 + c] = o;
}

__global__ __launch_bounds__(256) void pass_b_mean(const float* __restrict__ XL,
                                                   const float* __restrict__ EXA,
                                                   const float* __restrict__ M,
                                                   const float* __restrict__ DEN,
                                                   const float* __restrict__ bias,
                                                   const int* __restrict__ rowptr,
                                                   const int* __restrict__ col,
                                                   float* __restrict__ OUT, int n) {
    int wave = (blockIdx.x * blockDim.x + threadIdx.x) >> 6;
    int lane = threadIdx.x & 63;
    if (wave >= n) return;
    int dst = wave;
    int h = lane >> 4;
    float mh = M[dst * 4 + h];
    float rden = 1.0f / DEN[dst * 4 + h];
    int start = rowptr[dst], end = rowptr[dst + 1];
    float ax = 0.f, ay = 0.f;
    int c = lane * 2;
    for (int p = start; p < end; ++p) {
        int src = col[p];
        float lg = EXA[(size_t)p * 4 + h];
        float al = __expf(lg - mh) * rden;
        float2 xl = *(const float2*)&XL[(size_t)src * 128 + c];
        ax = fmaf(al, xl.x, ax);
        ay = fmaf(al, xl.y, ay);
    }
    // sum over the 4 heads: lanes l, l+16, l+32, l+48 hold the same within-head channels
    ax += __shfl_xor(ax, 16); ay += __shfl_xor(ay, 16);
    ax += __shfl_xor(ax, 32); ay += __shfl_xor(ay, 32);
    if (lane < 16) {
        int cc = lane * 2;
        float o0 = fmaxf(ax * 0.25f + bias[cc], 0.f);
        float o1 = fmaxf(ay * 0.25f + bias[cc + 1], 0.f);
        OUT[(size_t)dst * 32 + cc] = o0;
        OUT[(size_t)dst * 32 + cc + 1] = o1;
    }
}

// ---------------- launch ----------------

extern "C" void kernel_launch(void* const* d_in, const int* in_sizes, int n_in,
                              void* d_out, int out_size, void* d_ws, size_t ws_size,
                              hipStream_t stream) {
    const float* x   = (const float*)d_in[0];
    const int*   ei  = (const int*)d_in[1];
    const float* W1l = (const float*)d_in[2];
    const float* W1r = (const float*)d_in[3];
    const float* at1 = (const float*)d_in[4];
    const float* b1  = (const float*)d_in[5];
    const float* W2l = (const float*)d_in[6];
    const float* W2r = (const float*)d_in[7];
    const float* at2 = (const float*)d_in[8];
    const float* b2  = (const float*)d_in[9];
    const float* W3l = (const float*)d_in[10];
    const float* W3r = (const float*)d_in[11];
    const float* at3 = (const float*)d_in[12];
    const float* b3  = (const float*)d_in[13];
    float* out = (float*)d_out;

    int N = in_sizes[0] / 128;
    int E = in_sizes[1] / 2;
    int ET = E + N;
    const int* srcv = ei;
    const int* dstv = ei + E;

    // workspace carve (256B aligned)
    char* p = (char*)d_ws;
    auto alloc = [&](size_t bytes) -> void* {
        void* r = (void*)p;
        p += (bytes + 255) & ~(size_t)255;
        return r;
    };
    float* XL  = (float*)alloc((size_t)N * 128 * 4);
    float* XR  = (float*)alloc((size_t)N * 128 * 4);
    float* H   = (float*)alloc((size_t)N * 128 * 4);
    float* EXA = (float*)alloc((size_t)ET * 4 * 4);
    float* M   = (float*)alloc((size_t)N * 4 * 4);
    float* DEN = (float*)alloc((size_t)N * 4 * 4);
    int* rowptr = (int*)alloc((size_t)(N + 1) * 4);
    int* deg    = (int*)alloc((size_t)N * 4);
    int* dscan  = (int*)alloc((size_t)N * 4);
    int* cnt    = (int*)alloc((size_t)N * 4);
    int* bsum   = (int*)alloc(1024 * 4);
    int* boff   = (int*)alloc(1024 * 4);
    int* col    = (int*)alloc((size_t)ET * 4);

    // ---- CSR build ----
    k_init<<<(N + 255) / 256, 256, 0, stream>>>(deg, cnt, N);
    k_hist<<<(E + 255) / 256, 256, 0, stream>>>(dstv, deg, E);
    int nb = (N + 1023) / 1024;
    k_scan<<<nb, 256, 0, stream>>>(deg, dscan, bsum, N);
    k_scan<<<1, 256, 0, stream>>>(bsum, boff, nullptr, nb);
    k_scan_add<<<(N + 256) / 256, 256, 0, stream>>>(dscan, boff, rowptr, N, ET);
    k_fill<<<(ET + 255) / 256, 256, 0, stream>>>(srcv, dstv, rowptr, cnt, col, E, N);

    dim3 gg((N + 127) / 128, 2);
    int nwb = (N + 3) / 4;   // 4 waves (dsts) per 256-thread block

    // ---- layer 1 ----
    k_gemm<<<gg, 256, 0, stream>>>(x, W1l, W1r, XL, XR, N);
    pass_a<<<nwb, 256, 0, stream>>>(XL, XR, at1, rowptr, col, EXA, M, DEN, N);
    pass_b_cat<<<nwb, 256, 0, stream>>>(XL, EXA, M, DEN, b1, rowptr, col, H, N);
    // ---- layer 2 ----
    k_gemm<<<gg, 256, 0, stream>>>(H, W2l, W2r, XL, XR, N);
    pass_a<<<nwb, 256, 0, stream>>>(XL, XR, at2, rowptr, col, EXA, M, DEN, N);
    pass_b_cat<<<nwb, 256, 0, stream>>>(XL, EXA, M, DEN, b2, rowptr, col, H, N);
    // ---- layer 3 ----
    k_gemm<<<gg, 256, 0, stream>>>(H, W3l, W3r, XL, XR, N);
    pass_a<<<nwb, 256, 0, stream>>>(XL, XR, at3, rowptr, col, EXA, M, DEN, N);
    pass_b_mean<<<nwb, 256, 0, stream>>>(XL, EXA, M, DEN, b3, rowptr, col, out, N);
}

// Round 2
// 988.151 us; speedup vs baseline: 1.7485x; 1.7485x over previous
//
#include <hip/hip_runtime.h>
#include <hip/hip_bf16.h>

#define SLOPE 0.2f

// ---------------- CSR build ----------------

__global__ __launch_bounds__(256) void k_init(int* deg, int* cnt, int n) {
    int i = blockIdx.x * 256 + threadIdx.x;
    if (i < n) { deg[i] = 1; cnt[i] = 0; }   // deg starts at 1: self-loop
}

__global__ __launch_bounds__(256) void k_hist(const int* __restrict__ dstv, int* deg, int E) {
    int i = blockIdx.x * 256 + threadIdx.x;
    if (i < E) atomicAdd(&deg[dstv[i]], 1);
}

// exclusive scan of 1024-element chunks; block totals to bsums
__global__ __launch_bounds__(256) void k_scan(const int* __restrict__ in, int* __restrict__ out,
                                              int* bsums, int n) {
    __shared__ int wsum[4];
    int t = threadIdx.x;
    int base = blockIdx.x * 1024 + t * 4;
    int v0 = (base + 0 < n) ? in[base + 0] : 0;
    int v1 = (base + 1 < n) ? in[base + 1] : 0;
    int v2 = (base + 2 < n) ? in[base + 2] : 0;
    int v3 = (base + 3 < n) ? in[base + 3] : 0;
    int tsum = v0 + v1 + v2 + v3;
    int lane = t & 63, wid = t >> 6;
    int x = tsum;
    #pragma unroll
    for (int d = 1; d < 64; d <<= 1) {
        int y = __shfl_up(x, d);
        if (lane >= d) x += y;
    }
    if (lane == 63) wsum[wid] = x;
    __syncthreads();
    if (t == 0) {
        int a = 0;
        for (int w = 0; w < 4; ++w) { int b = wsum[w]; wsum[w] = a; a += b; }
    }
    __syncthreads();
    int excl = x - tsum + wsum[wid];
    if (base + 0 < n) out[base + 0] = excl;
    if (base + 1 < n) out[base + 1] = excl + v0;
    if (base + 2 < n) out[base + 2] = excl + v0 + v1;
    if (base + 3 < n) out[base + 3] = excl + v0 + v1 + v2;
    if (bsums != nullptr && t == 255) bsums[blockIdx.x] = excl + tsum;
}

__global__ __launch_bounds__(256) void k_scan_add(const int* __restrict__ dscan,
                                                  const int* __restrict__ boff,
                                                  int* __restrict__ rowptr, int n, int total) {
    int i = blockIdx.x * 256 + threadIdx.x;
    if (i < n) rowptr[i] = dscan[i] + boff[i >> 10];
    if (i == n) rowptr[n] = total;
}

__global__ __launch_bounds__(256) void k_fill(const int* __restrict__ srcv, const int* __restrict__ dstv,
                                              const int* __restrict__ rowptr, int* cnt, int* col,
                                              int E, int n) {
    int i = blockIdx.x * 256 + threadIdx.x;
    if (i < E) {
        int d = dstv[i];
        int pos = rowptr[d] + atomicAdd(&cnt[d], 1);
        col[pos] = srcv[i];
    } else if (i < E + n) {
        int d = i - E;
        int pos = rowptr[d] + atomicAdd(&cnt[d], 1);
        col[pos] = d;
    }
}

// ---------------- fp32 GEMM: Y = X(nrows x 128) @ W(128 x 128) ----------------

__global__ __launch_bounds__(256) void k_gemm(const float* __restrict__ X,
                                              const float* __restrict__ W0,
                                              const float* __restrict__ W1,
                                              float* __restrict__ Y0, float* __restrict__ Y1,
                                              int nrows) {
    const float* __restrict__ W = blockIdx.y ? W1 : W0;
    float* __restrict__ Y = blockIdx.y ? Y1 : Y0;
    __shared__ float Xs[16][132];
    __shared__ float Ws[16][132];
    int row0 = blockIdx.x * 128;
    int t = threadIdx.x;
    int tx = t & 15, ty = t >> 4;
    float acc[8][8];
    #pragma unroll
    for (int i = 0; i < 8; ++i)
        #pragma unroll
        for (int j = 0; j < 8; ++j) acc[i][j] = 0.f;

    for (int k0 = 0; k0 < 128; k0 += 16) {
        {
            int r = t >> 2;
            int kq = (t & 3) * 4;
            #pragma unroll
            for (int rr = 0; rr < 2; ++rr) {
                int row = row0 + r + rr * 64;
                float4 xv = (row < nrows) ? *(const float4*)&X[(size_t)row * 128 + k0 + kq]
                                          : make_float4(0.f, 0.f, 0.f, 0.f);
                Xs[kq + 0][r + rr * 64] = xv.x;
                Xs[kq + 1][r + rr * 64] = xv.y;
                Xs[kq + 2][r + rr * 64] = xv.z;
                Xs[kq + 3][r + rr * 64] = xv.w;
            }
        }
        {
            int kk = t >> 5;
            int c4 = (t & 31) * 4;
            #pragma unroll
            for (int rr = 0; rr < 2; ++rr) {
                int k = kk + rr * 8;
                *(float4*)&Ws[k][c4] = *(const float4*)&W[(size_t)(k0 + k) * 128 + c4];
            }
        }
        __syncthreads();
        #pragma unroll
        for (int k = 0; k < 16; ++k) {
            float a[8], b[8];
            *(float4*)&a[0] = *(const float4*)&Xs[k][ty * 8];
            *(float4*)&a[4] = *(const float4*)&Xs[k][ty * 8 + 4];
            *(float4*)&b[0] = *(const float4*)&Ws[k][tx * 8];
            *(float4*)&b[4] = *(const float4*)&Ws[k][tx * 8 + 4];
            #pragma unroll
            for (int i = 0; i < 8; ++i)
                #pragma unroll
                for (int j = 0; j < 8; ++j) acc[i][j] = fmaf(a[i], b[j], acc[i][j]);
        }
        __syncthreads();
    }
    #pragma unroll
    for (int i = 0; i < 8; ++i) {
        int row = row0 + ty * 8 + i;
        if (row < nrows) {
            *(float4*)&Y[(size_t)row * 128 + tx * 8]     = *(float4*)&acc[i][0];
            *(float4*)&Y[(size_t)row * 128 + tx * 8 + 4] = *(float4*)&acc[i][4];
        }
    }
}

// ---------------- fused attention: online softmax + weighted aggregation ----------------
// One wave per dst. lane owns channels c=2*lane, 2*lane+1 (head = lane>>4).
// Running (m, s) are identical across the 16 lanes of a head group (logit is
// broadcast by the shfl reduction), so each lane rescales its own accumulator.

template <bool MEAN>
__global__ __launch_bounds__(256) void fused_gat(const float* __restrict__ XL,
                                                 const float* __restrict__ XR,
                                                 const float* __restrict__ att,
                                                 const float* __restrict__ bias,
                                                 const int* __restrict__ rowptr,
                                                 const int* __restrict__ col,
                                                 float* __restrict__ OUT, int n) {
    int wave = (blockIdx.x * blockDim.x + threadIdx.x) >> 6;
    int lane = threadIdx.x & 63;
    if (wave >= n) return;
    int dst = wave;
    int start = rowptr[dst], end = rowptr[dst + 1];
    int c = lane * 2;
    float2 xr = *(const float2*)&XR[(size_t)dst * 128 + c];
    float2 av = *(const float2*)&att[c];
    float m = -3.0e38f, s = 0.f, ax = 0.f, ay = 0.f;

    int p = start;
    // unroll by 2: two independent gathers in flight
    for (; p + 1 < end; p += 2) {
        int s0 = col[p], s1 = col[p + 1];
        float2 x0 = *(const float2*)&XL[(size_t)s0 * 128 + c];
        float2 x1 = *(const float2*)&XL[(size_t)s1 * 128 + c];
        float u0 = x0.x + xr.x, u1 = x0.y + xr.y;
        float v0 = x1.x + xr.x, v1 = x1.y + xr.y;
        u0 = (u0 > 0.f) ? u0 : u0 * SLOPE;
        u1 = (u1 > 0.f) ? u1 : u1 * SLOPE;
        v0 = (v0 > 0.f) ? v0 : v0 * SLOPE;
        v1 = (v1 > 0.f) ? v1 : v1 * SLOPE;
        float t0 = u0 * av.x + u1 * av.y;
        float t1 = v0 * av.x + v1 * av.y;
        #pragma unroll
        for (int d = 1; d < 16; d <<= 1) {
            t0 += __shfl_xor(t0, d);
            t1 += __shfl_xor(t1, d);
        }
        // merge edge 0
        if (t0 > m) {
            float r = __expf(m - t0);
            s = fmaf(s, r, 1.f);
            ax = fmaf(ax, r, x0.x);
            ay = fmaf(ay, r, x0.y);
            m = t0;
        } else {
            float w = __expf(t0 - m);
            s += w;
            ax = fmaf(w, x0.x, ax);
            ay = fmaf(w, x0.y, ay);
        }
        // merge edge 1
        if (t1 > m) {
            float r = __expf(m - t1);
            s = fmaf(s, r, 1.f);
            ax = fmaf(ax, r, x1.x);
            ay = fmaf(ay, r, x1.y);
            m = t1;
        } else {
            float w = __expf(t1 - m);
            s += w;
            ax = fmaf(w, x1.x, ax);
            ay = fmaf(w, x1.y, ay);
        }
    }
    for (; p < end; ++p) {
        int s0 = col[p];
        float2 x0 = *(const float2*)&XL[(size_t)s0 * 128 + c];
        float u0 = x0.x + xr.x, u1 = x0.y + xr.y;
        u0 = (u0 > 0.f) ? u0 : u0 * SLOPE;
        u1 = (u1 > 0.f) ? u1 : u1 * SLOPE;
        float t0 = u0 * av.x + u1 * av.y;
        #pragma unroll
        for (int d = 1; d < 16; d <<= 1) t0 += __shfl_xor(t0, d);
        if (t0 > m) {
            float r = __expf(m - t0);
            s = fmaf(s, r, 1.f);
            ax = fmaf(ax, r, x0.x);
            ay = fmaf(ay, r, x0.y);
            m = t0;
        } else {
            float w = __expf(t0 - m);
            s += w;
            ax = fmaf(w, x0.x, ax);
            ay = fmaf(w, x0.y, ay);
        }
    }

    float rs = 1.0f / s;
    ax *= rs;
    ay *= rs;
    if (MEAN) {
        // sum normalized per-head values across the 4 head groups
        ax += __shfl_xor(ax, 16); ay += __shfl_xor(ay, 16);
        ax += __shfl_xor(ax, 32); ay += __shfl_xor(ay, 32);
        if (lane < 16) {
            int cc = lane * 2;
            float o0 = fmaxf(ax * 0.25f + bias[cc], 0.f);
            float o1 = fmaxf(ay * 0.25f + bias[cc + 1], 0.f);
            OUT[(size_t)dst * 32 + cc] = o0;
            OUT[(size_t)dst * 32 + cc + 1] = o1;
        }
    } else {
        float o0 = fmaxf(ax + bias[c], 0.f);
        float o1 = fmaxf(ay + bias[c + 1], 0.f);
        *(float2*)&OUT[(size_t)dst * 128 + c] = make_float2(o0, o1);
    }
}

// ---------------- launch ----------------

extern "C" void kernel_launch(void* const* d_in, const int* in_sizes, int n_in,
                              void* d_out, int out_size, void* d_ws, size_t ws_size,
                              hipStream_t stream) {
    const float* x   = (const float*)d_in[0];
    const int*   ei  = (const int*)d_in[1];
    const float* W1l = (const float*)d_in[2];
    const float* W1r = (const float*)d_in[3];
    const float* at1 = (const float*)d_in[4];
    const float* b1  = (const float*)d_in[5];
    const float* W2l = (const float*)d_in[6];
    const float* W2r = (const float*)d_in[7];
    const float* at2 = (const float*)d_in[8];
    const float* b2  = (const float*)d_in[9];
    const float* W3l = (const float*)d_in[10];
    const float* W3r = (const float*)d_in[11];
    const float* at3 = (const float*)d_in[12];
    const float* b3  = (const float*)d_in[13];
    float* out = (float*)d_out;

    int N = in_sizes[0] / 128;
    int E = in_sizes[1] / 2;
    int ET = E + N;
    const int* srcv = ei;
    const int* dstv = ei + E;

    char* p = (char*)d_ws;
    auto alloc = [&](size_t bytes) -> void* {
        void* r = (void*)p;
        p += (bytes + 255) & ~(size_t)255;
        return r;
    };
    float* XL  = (float*)alloc((size_t)N * 128 * 4);
    float* XR  = (float*)alloc((size_t)N * 128 * 4);
    float* H   = (float*)alloc((size_t)N * 128 * 4);
    int* rowptr = (int*)alloc((size_t)(N + 1) * 4);
    int* deg    = (int*)alloc((size_t)N * 4);
    int* dscan  = (int*)alloc((size_t)N * 4);
    int* cnt    = (int*)alloc((size_t)N * 4);
    int* bsum   = (int*)alloc(1024 * 4);
    int* boff   = (int*)alloc(1024 * 4);
    int* col    = (int*)alloc((size_t)ET * 4);

    // ---- CSR build ----
    k_init<<<(N + 255) / 256, 256, 0, stream>>>(deg, cnt, N);
    k_hist<<<(E + 255) / 256, 256, 0, stream>>>(dstv, deg, E);
    int nb = (N + 1023) / 1024;
    k_scan<<<nb, 256, 0, stream>>>(deg, dscan, bsum, N);
    k_scan<<<1, 256, 0, stream>>>(bsum, boff, nullptr, nb);
    k_scan_add<<<(N + 256) / 256, 256, 0, stream>>>(dscan, boff, rowptr, N, ET);
    k_fill<<<(ET + 255) / 256, 256, 0, stream>>>(srcv, dstv, rowptr, cnt, col, E, N);

    dim3 gg((N + 127) / 128, 2);
    int nwb = (N + 3) / 4;   // 4 waves (dsts) per 256-thread block

    // ---- layer 1 ----
    k_gemm<<<gg, 256, 0, stream>>>(x, W1l, W1r, XL, XR, N);
    fused_gat<false><<<nwb, 256, 0, stream>>>(XL, XR, at1, b1, rowptr, col, H, N);
    // ---- layer 2 ----
    k_gemm<<<gg, 256, 0, stream>>>(H, W2l, W2r, XL, XR, N);
    fused_gat<false><<<nwb, 256, 0, stream>>>(XL, XR, at2, b2, rowptr, col, H, N);
    // ---- layer 3 ----
    k_gemm<<<gg, 256, 0, stream>>>(H, W3l, W3r, XL, XR, N);
    fused_gat<true><<<nwb, 256, 0, stream>>>(XL, XR, at3, b3, rowptr, col, out, N);
}

// Round 3
// 925.583 us; speedup vs baseline: 1.8667x; 1.0676x over previous
//
#include <hip/hip_runtime.h>
#include <hip/hip_bf16.h>

#define SLOPE 0.2f

// ---------------- CSR build ----------------

__global__ __launch_bounds__(256) void k_init(int* deg, int* cnt, int n) {
    int i = blockIdx.x * 256 + threadIdx.x;
    if (i < n) { deg[i] = 1; cnt[i] = 0; }   // deg starts at 1: self-loop
}

__global__ __launch_bounds__(256) void k_hist(const int* __restrict__ dstv, int* deg, int E) {
    int i = blockIdx.x * 256 + threadIdx.x;
    if (i < E) atomicAdd(&deg[dstv[i]], 1);
}

// exclusive scan of 1024-element chunks; block totals to bsums
__global__ __launch_bounds__(256) void k_scan(const int* __restrict__ in, int* __restrict__ out,
                                              int* bsums, int n) {
    __shared__ int wsum[4];
    int t = threadIdx.x;
    int base = blockIdx.x * 1024 + t * 4;
    int v0 = (base + 0 < n) ? in[base + 0] : 0;
    int v1 = (base + 1 < n) ? in[base + 1] : 0;
    int v2 = (base + 2 < n) ? in[base + 2] : 0;
    int v3 = (base + 3 < n) ? in[base + 3] : 0;
    int tsum = v0 + v1 + v2 + v3;
    int lane = t & 63, wid = t >> 6;
    int x = tsum;
    #pragma unroll
    for (int d = 1; d < 64; d <<= 1) {
        int y = __shfl_up(x, d);
        if (lane >= d) x += y;
    }
    if (lane == 63) wsum[wid] = x;
    __syncthreads();
    if (t == 0) {
        int a = 0;
        for (int w = 0; w < 4; ++w) { int b = wsum[w]; wsum[w] = a; a += b; }
    }
    __syncthreads();
    int excl = x - tsum + wsum[wid];
    if (base + 0 < n) out[base + 0] = excl;
    if (base + 1 < n) out[base + 1] = excl + v0;
    if (base + 2 < n) out[base + 2] = excl + v0 + v1;
    if (base + 3 < n) out[base + 3] = excl + v0 + v1 + v2;
    if (bsums != nullptr && t == 255) bsums[blockIdx.x] = excl + tsum;
}

__global__ __launch_bounds__(256) void k_scan_add(const int* __restrict__ dscan,
                                                  const int* __restrict__ boff,
                                                  int* __restrict__ rowptr, int n, int total) {
    int i = blockIdx.x * 256 + threadIdx.x;
    if (i < n) rowptr[i] = dscan[i] + boff[i >> 10];
    if (i == n) rowptr[n] = total;
}

__global__ __launch_bounds__(256) void k_fill(const int* __restrict__ srcv, const int* __restrict__ dstv,
                                              const int* __restrict__ rowptr, int* cnt, int* col,
                                              int E, int n) {
    int i = blockIdx.x * 256 + threadIdx.x;
    if (i < E) {
        int d = dstv[i];
        int pos = rowptr[d] + atomicAdd(&cnt[d], 1);
        col[pos] = srcv[i];
    } else if (i < E + n) {
        int d = i - E;
        int pos = rowptr[d] + atomicAdd(&cnt[d], 1);
        col[pos] = d;
    }
}

// ---------------- fp32 GEMM: Y = X(nrows x 128) @ W(128 x 128) ----------------

__global__ __launch_bounds__(256) void k_gemm(const float* __restrict__ X,
                                              const float* __restrict__ W0,
                                              const float* __restrict__ W1,
                                              float* __restrict__ Y0, float* __restrict__ Y1,
                                              int nrows) {
    const float* __restrict__ W = blockIdx.y ? W1 : W0;
    float* __restrict__ Y = blockIdx.y ? Y1 : Y0;
    __shared__ float Xs[16][132];
    __shared__ float Ws[16][132];
    int row0 = blockIdx.x * 128;
    int t = threadIdx.x;
    int tx = t & 15, ty = t >> 4;
    float acc[8][8];
    #pragma unroll
    for (int i = 0; i < 8; ++i)
        #pragma unroll
        for (int j = 0; j < 8; ++j) acc[i][j] = 0.f;

    for (int k0 = 0; k0 < 128; k0 += 16) {
        {
            int r = t >> 2;
            int kq = (t & 3) * 4;
            #pragma unroll
            for (int rr = 0; rr < 2; ++rr) {
                int row = row0 + r + rr * 64;
                float4 xv = (row < nrows) ? *(const float4*)&X[(size_t)row * 128 + k0 + kq]
                                          : make_float4(0.f, 0.f, 0.f, 0.f);
                Xs[kq + 0][r + rr * 64] = xv.x;
                Xs[kq + 1][r + rr * 64] = xv.y;
                Xs[kq + 2][r + rr * 64] = xv.z;
                Xs[kq + 3][r + rr * 64] = xv.w;
            }
        }
        {
            int kk = t >> 5;
            int c4 = (t & 31) * 4;
            #pragma unroll
            for (int rr = 0; rr < 2; ++rr) {
                int k = kk + rr * 8;
                *(float4*)&Ws[k][c4] = *(const float4*)&W[(size_t)(k0 + k) * 128 + c4];
            }
        }
        __syncthreads();
        #pragma unroll
        for (int k = 0; k < 16; ++k) {
            float a[8], b[8];
            *(float4*)&a[0] = *(const float4*)&Xs[k][ty * 8];
            *(float4*)&a[4] = *(const float4*)&Xs[k][ty * 8 + 4];
            *(float4*)&b[0] = *(const float4*)&Ws[k][tx * 8];
            *(float4*)&b[4] = *(const float4*)&Ws[k][tx * 8 + 4];
            #pragma unroll
            for (int i = 0; i < 8; ++i)
                #pragma unroll
                for (int j = 0; j < 8; ++j) acc[i][j] = fmaf(a[i], b[j], acc[i][j]);
        }
        __syncthreads();
    }
    #pragma unroll
    for (int i = 0; i < 8; ++i) {
        int row = row0 + ty * 8 + i;
        if (row < nrows) {
            *(float4*)&Y[(size_t)row * 128 + tx * 8]     = *(float4*)&acc[i][0];
            *(float4*)&Y[(size_t)row * 128 + tx * 8 + 4] = *(float4*)&acc[i][4];
        }
    }
}

// ---------------- fused attention ----------------
// One wave per dst. lane owns channels c=2*lane, 2*lane+1 (head = lane>>4).
// No running max: logits are bounded (clamped at 80); softmax normalizes at the end.
// Cross-lane logit reduction via DPP row_ror (full-rate VALU, no LDS pipe).

__device__ __forceinline__ float dpp_ror_add(float v, const int ctrl) {
    // v += rotate_right_within_row16(v, n); bound_ctrl=true
    switch (ctrl) {
        case 1: return v + __int_as_float(__builtin_amdgcn_update_dpp(0, __float_as_int(v), 0x121, 0xf, 0xf, true));
        case 2: return v + __int_as_float(__builtin_amdgcn_update_dpp(0, __float_as_int(v), 0x122, 0xf, 0xf, true));
        case 4: return v + __int_as_float(__builtin_amdgcn_update_dpp(0, __float_as_int(v), 0x124, 0xf, 0xf, true));
        default: return v + __int_as_float(__builtin_amdgcn_update_dpp(0, __float_as_int(v), 0x128, 0xf, 0xf, true));
    }
}

__device__ __forceinline__ float rowsum16(float t) {
    t = dpp_ror_add(t, 1);
    t = dpp_ror_add(t, 2);
    t = dpp_ror_add(t, 4);
    t = dpp_ror_add(t, 8);
    return t;   // all 16 lanes of the row hold the row sum
}

template <bool MEAN>
__global__ __launch_bounds__(256) void fused_gat(const float* __restrict__ XL,
                                                 const float* __restrict__ XR,
                                                 const float* __restrict__ att,
                                                 const float* __restrict__ bias,
                                                 const int* __restrict__ rowptr,
                                                 const int* __restrict__ col,
                                                 float* __restrict__ OUT, int n) {
    int wave = (blockIdx.x * blockDim.x + threadIdx.x) >> 6;
    int lane = threadIdx.x & 63;
    if (wave >= n) return;
    int dst = wave;
    int start = rowptr[dst], end = rowptr[dst + 1];
    int c = lane * 2;
    float2 xr = *(const float2*)&XR[(size_t)dst * 128 + c];
    float2 av = *(const float2*)&att[c];
    float s = 0.f, ax = 0.f, ay = 0.f;

    int p = start;
    for (; p + 3 < end; p += 4) {
        int i0 = col[p], i1 = col[p + 1], i2 = col[p + 2], i3 = col[p + 3];
        float2 x0 = *(const float2*)&XL[(size_t)i0 * 128 + c];
        float2 x1 = *(const float2*)&XL[(size_t)i1 * 128 + c];
        float2 x2 = *(const float2*)&XL[(size_t)i2 * 128 + c];
        float2 x3 = *(const float2*)&XL[(size_t)i3 * 128 + c];
        float u0x = x0.x + xr.x, u0y = x0.y + xr.y;
        float u1x = x1.x + xr.x, u1y = x1.y + xr.y;
        float u2x = x2.x + xr.x, u2y = x2.y + xr.y;
        float u3x = x3.x + xr.x, u3y = x3.y + xr.y;
        // leaky_relu(u) = max(u, SLOPE*u)
        u0x = fmaxf(u0x, SLOPE * u0x); u0y = fmaxf(u0y, SLOPE * u0y);
        u1x = fmaxf(u1x, SLOPE * u1x); u1y = fmaxf(u1y, SLOPE * u1y);
        u2x = fmaxf(u2x, SLOPE * u2x); u2y = fmaxf(u2y, SLOPE * u2y);
        u3x = fmaxf(u3x, SLOPE * u3x); u3y = fmaxf(u3y, SLOPE * u3y);
        float t0 = fmaf(u0x, av.x, u0y * av.y);
        float t1 = fmaf(u1x, av.x, u1y * av.y);
        float t2 = fmaf(u2x, av.x, u2y * av.y);
        float t3 = fmaf(u3x, av.x, u3y * av.y);
        t0 = rowsum16(t0); t1 = rowsum16(t1);
        t2 = rowsum16(t2); t3 = rowsum16(t3);
        float w0 = __expf(fminf(t0, 80.f));
        float w1 = __expf(fminf(t1, 80.f));
        float w2 = __expf(fminf(t2, 80.f));
        float w3 = __expf(fminf(t3, 80.f));
        s += (w0 + w1) + (w2 + w3);
        ax = fmaf(w0, x0.x, ax); ay = fmaf(w0, x0.y, ay);
        ax = fmaf(w1, x1.x, ax); ay = fmaf(w1, x1.y, ay);
        ax = fmaf(w2, x2.x, ax); ay = fmaf(w2, x2.y, ay);
        ax = fmaf(w3, x3.x, ax); ay = fmaf(w3, x3.y, ay);
    }
    for (; p < end; ++p) {
        int i0 = col[p];
        float2 x0 = *(const float2*)&XL[(size_t)i0 * 128 + c];
        float u0x = x0.x + xr.x, u0y = x0.y + xr.y;
        u0x = fmaxf(u0x, SLOPE * u0x); u0y = fmaxf(u0y, SLOPE * u0y);
        float t0 = fmaf(u0x, av.x, u0y * av.y);
        t0 = rowsum16(t0);
        float w0 = __expf(fminf(t0, 80.f));
        s += w0;
        ax = fmaf(w0, x0.x, ax); ay = fmaf(w0, x0.y, ay);
    }

    float rs = 1.0f / s;
    ax *= rs;
    ay *= rs;
    if (MEAN) {
        ax += __shfl_xor(ax, 16); ay += __shfl_xor(ay, 16);
        ax += __shfl_xor(ax, 32); ay += __shfl_xor(ay, 32);
        if (lane < 16) {
            int cc = lane * 2;
            float o0 = fmaxf(ax * 0.25f + bias[cc], 0.f);
            float o1 = fmaxf(ay * 0.25f + bias[cc + 1], 0.f);
            OUT[(size_t)dst * 32 + cc] = o0;
            OUT[(size_t)dst * 32 + cc + 1] = o1;
        }
    } else {
        float o0 = fmaxf(ax + bias[c], 0.f);
        float o1 = fmaxf(ay + bias[c + 1], 0.f);
        *(float2*)&OUT[(size_t)dst * 128 + c] = make_float2(o0, o1);
    }
}

// ---------------- launch ----------------

extern "C" void kernel_launch(void* const* d_in, const int* in_sizes, int n_in,
                              void* d_out, int out_size, void* d_ws, size_t ws_size,
                              hipStream_t stream) {
    const float* x   = (const float*)d_in[0];
    const int*   ei  = (const int*)d_in[1];
    const float* W1l = (const float*)d_in[2];
    const float* W1r = (const float*)d_in[3];
    const float* at1 = (const float*)d_in[4];
    const float* b1  = (const float*)d_in[5];
    const float* W2l = (const float*)d_in[6];
    const float* W2r = (const float*)d_in[7];
    const float* at2 = (const float*)d_in[8];
    const float* b2  = (const float*)d_in[9];
    const float* W3l = (const float*)d_in[10];
    const float* W3r = (const float*)d_in[11];
    const float* at3 = (const float*)d_in[12];
    const float* b3  = (const float*)d_in[13];
    float* out = (float*)d_out;

    int N = in_sizes[0] / 128;
    int E = in_sizes[1] / 2;
    int ET = E + N;
    const int* srcv = ei;
    const int* dstv = ei + E;

    char* p = (char*)d_ws;
    auto alloc = [&](size_t bytes) -> void* {
        void* r = (void*)p;
        p += (bytes + 255) & ~(size_t)255;
        return r;
    };
    float* XL  = (float*)alloc((size_t)N * 128 * 4);
    float* XR  = (float*)alloc((size_t)N * 128 * 4);
    float* H   = (float*)alloc((size_t)N * 128 * 4);
    int* rowptr = (int*)alloc((size_t)(N + 1) * 4);
    int* deg    = (int*)alloc((size_t)N * 4);
    int* dscan  = (int*)alloc((size_t)N * 4);
    int* cnt    = (int*)alloc((size_t)N * 4);
    int* bsum   = (int*)alloc(1024 * 4);
    int* boff   = (int*)alloc(1024 * 4);
    int* col    = (int*)alloc((size_t)ET * 4);

    // ---- CSR build ----
    k_init<<<(N + 255) / 256, 256, 0, stream>>>(deg, cnt, N);
    k_hist<<<(E + 255) / 256, 256, 0, stream>>>(dstv, deg, E);
    int nb = (N + 1023) / 1024;
    k_scan<<<nb, 256, 0, stream>>>(deg, dscan, bsum, N);
    k_scan<<<1, 256, 0, stream>>>(bsum, boff, nullptr, nb);
    k_scan_add<<<(N + 256) / 256, 256, 0, stream>>>(dscan, boff, rowptr, N, ET);
    k_fill<<<(ET + 255) / 256, 256, 0, stream>>>(srcv, dstv, rowptr, cnt, col, E, N);

    dim3 gg((N + 127) / 128, 2);
    int nwb = (N + 3) / 4;   // 4 waves (dsts) per 256-thread block

    // ---- layer 1 ----
    k_gemm<<<gg, 256, 0, stream>>>(x, W1l, W1r, XL, XR, N);
    fused_gat<false><<<nwb, 256, 0, stream>>>(XL, XR, at1, b1, rowptr, col, H, N);
    // ---- layer 2 ----
    k_gemm<<<gg, 256, 0, stream>>>(H, W2l, W2r, XL, XR, N);
    fused_gat<false><<<nwb, 256, 0, stream>>>(XL, XR, at2, b2, rowptr, col, H, N);
    // ---- layer 3 ----
    k_gemm<<<gg, 256, 0, stream>>>(H, W3l, W3r, XL, XR, N);
    fused_gat<true><<<nwb, 256, 0, stream>>>(XL, XR, at3, b3, rowptr, col, out, N);
}

// Round 4
// 795.518 us; speedup vs baseline: 2.1719x; 1.1635x over previous
//
#include <hip/hip_runtime.h>
#include <hip/hip_bf16.h>
#include <hip/hip_fp16.h>

#define SLOPE 0.2f

// ---------------- CSR build ----------------

__global__ __launch_bounds__(256) void k_init(int* deg, int* cnt, int n) {
    int i = blockIdx.x * 256 + threadIdx.x;
    if (i < n) { deg[i] = 1; cnt[i] = 0; }   // deg starts at 1: self-loop
}

__global__ __launch_bounds__(256) void k_hist(const int* __restrict__ dstv, int* deg, int E) {
    int i = blockIdx.x * 256 + threadIdx.x;
    if (i < E) atomicAdd(&deg[dstv[i]], 1);
}

__global__ __launch_bounds__(256) void k_scan(const int* __restrict__ in, int* __restrict__ out,
                                              int* bsums, int n) {
    __shared__ int wsum[4];
    int t = threadIdx.x;
    int base = blockIdx.x * 1024 + t * 4;
    int v0 = (base + 0 < n) ? in[base + 0] : 0;
    int v1 = (base + 1 < n) ? in[base + 1] : 0;
    int v2 = (base + 2 < n) ? in[base + 2] : 0;
    int v3 = (base + 3 < n) ? in[base + 3] : 0;
    int tsum = v0 + v1 + v2 + v3;
    int lane = t & 63, wid = t >> 6;
    int x = tsum;
    #pragma unroll
    for (int d = 1; d < 64; d <<= 1) {
        int y = __shfl_up(x, d);
        if (lane >= d) x += y;
    }
    if (lane == 63) wsum[wid] = x;
    __syncthreads();
    if (t == 0) {
        int a = 0;
        for (int w = 0; w < 4; ++w) { int b = wsum[w]; wsum[w] = a; a += b; }
    }
    __syncthreads();
    int excl = x - tsum + wsum[wid];
    if (base + 0 < n) out[base + 0] = excl;
    if (base + 1 < n) out[base + 1] = excl + v0;
    if (base + 2 < n) out[base + 2] = excl + v0 + v1;
    if (base + 3 < n) out[base + 3] = excl + v0 + v1 + v2;
    if (bsums != nullptr && t == 255) bsums[blockIdx.x] = excl + tsum;
}

__global__ __launch_bounds__(256) void k_scan_add(const int* __restrict__ dscan,
                                                  const int* __restrict__ boff,
                                                  int* __restrict__ rowptr, int n, int total) {
    int i = blockIdx.x * 256 + threadIdx.x;
    if (i < n) rowptr[i] = dscan[i] + boff[i >> 10];
    if (i == n) rowptr[n] = total;
}

__global__ __launch_bounds__(256) void k_fill(const int* __restrict__ srcv, const int* __restrict__ dstv,
                                              const int* __restrict__ rowptr, int* cnt, int* col,
                                              int E, int n) {
    int i = blockIdx.x * 256 + threadIdx.x;
    if (i < E) {
        int d = dstv[i];
        int pos = rowptr[d] + atomicAdd(&cnt[d], 1);
        col[pos] = srcv[i];
    } else if (i < E + n) {
        int d = i - E;
        int pos = rowptr[d] + atomicAdd(&cnt[d], 1);
        col[pos] = d;
    }
}

// ---------------- fp32 GEMM: Y0(half) = X@W0, Y1(float) = X@W1 ----------------
// 128x128 tile, 256 thr, 8x8 acc, register-prefetch pipeline.

__global__ __launch_bounds__(256) void k_gemm(const float* __restrict__ X,
                                              const float* __restrict__ W0,
                                              const float* __restrict__ W1,
                                              __half* __restrict__ Y0, float* __restrict__ Y1,
                                              int nrows) {
    const float* __restrict__ W = blockIdx.y ? W1 : W0;
    __shared__ float Xs[16][132];
    __shared__ float Ws[16][132];
    int row0 = blockIdx.x * 128;
    int t = threadIdx.x;
    int tx = t & 15, ty = t >> 4;
    int r = t >> 2;             // X loader: row within tile
    int kq = (t & 3) * 4;       // X loader: k quad
    int kk = t >> 5;            // W loader: k row
    int c4 = (t & 31) * 4;      // W loader: col quad
    float acc[8][8];
    #pragma unroll
    for (int i = 0; i < 8; ++i)
        #pragma unroll
        for (int j = 0; j < 8; ++j) acc[i][j] = 0.f;

    float4 px[2], pw[2];
    #pragma unroll
    for (int rr = 0; rr < 2; ++rr) {
        int row = row0 + r + rr * 64;
        px[rr] = (row < nrows) ? *(const float4*)&X[(size_t)row * 128 + kq]
                               : make_float4(0.f, 0.f, 0.f, 0.f);
        pw[rr] = *(const float4*)&W[(size_t)(kk + rr * 8) * 128 + c4];
    }

    for (int k0 = 0; k0 < 128; k0 += 16) {
        #pragma unroll
        for (int rr = 0; rr < 2; ++rr) {
            Xs[kq + 0][r + rr * 64] = px[rr].x;
            Xs[kq + 1][r + rr * 64] = px[rr].y;
            Xs[kq + 2][r + rr * 64] = px[rr].z;
            Xs[kq + 3][r + rr * 64] = px[rr].w;
            *(float4*)&Ws[kk + rr * 8][c4] = pw[rr];
        }
        __syncthreads();
        if (k0 + 16 < 128) {
            #pragma unroll
            for (int rr = 0; rr < 2; ++rr) {
                int row = row0 + r + rr * 64;
                px[rr] = (row < nrows) ? *(const float4*)&X[(size_t)row * 128 + k0 + 16 + kq]
                                       : make_float4(0.f, 0.f, 0.f, 0.f);
                pw[rr] = *(const float4*)&W[(size_t)(k0 + 16 + kk + rr * 8) * 128 + c4];
            }
        }
        #pragma unroll
        for (int k = 0; k < 16; ++k) {
            float a[8], b[8];
            *(float4*)&a[0] = *(const float4*)&Xs[k][ty * 8];
            *(float4*)&a[4] = *(const float4*)&Xs[k][ty * 8 + 4];
            *(float4*)&b[0] = *(const float4*)&Ws[k][tx * 8];
            *(float4*)&b[4] = *(const float4*)&Ws[k][tx * 8 + 4];
            #pragma unroll
            for (int i = 0; i < 8; ++i)
                #pragma unroll
                for (int j = 0; j < 8; ++j) acc[i][j] = fmaf(a[i], b[j], acc[i][j]);
        }
        __syncthreads();
    }

    if (blockIdx.y == 0) {
        #pragma unroll
        for (int i = 0; i < 8; ++i) {
            int row = row0 + ty * 8 + i;
            if (row < nrows) {
                union { __half2 h2[4]; uint4 u; } cv;
                #pragma unroll
                for (int q = 0; q < 4; ++q)
                    cv.h2[q] = __floats2half2_rn(acc[i][2 * q], acc[i][2 * q + 1]);
                *(uint4*)&Y0[(size_t)row * 128 + tx * 8] = cv.u;
            }
        }
    } else {
        #pragma unroll
        for (int i = 0; i < 8; ++i) {
            int row = row0 + ty * 8 + i;
            if (row < nrows) {
                *(float4*)&Y1[(size_t)row * 128 + tx * 8]     = *(float4*)&acc[i][0];
                *(float4*)&Y1[(size_t)row * 128 + tx * 8 + 4] = *(float4*)&acc[i][4];
            }
        }
    }
}

// ---------------- fused attention: 4 dsts per wave ----------------
// group g = lane>>4 owns dst = wave*4+g; sub = lane&15 owns channels sub*8..sub*8+7.
// head = sub>>2, so each head's 32 channels live in one aligned DPP quad ->
// logit reduction = 2 quad_perm adds serving 4 edges (one per group) at once.

__device__ __forceinline__ float quadsum(float t) {
    t += __int_as_float(__builtin_amdgcn_update_dpp(0, __float_as_int(t), 0xB1, 0xf, 0xf, true)); // [1,0,3,2]
    t += __int_as_float(__builtin_amdgcn_update_dpp(0, __float_as_int(t), 0x4E, 0xf, 0xf, true)); // [2,3,0,1]
    return t;
}

template <bool MEAN>
__global__ __launch_bounds__(256) void fused_gat(const __half* __restrict__ XLh,
                                                 const float* __restrict__ XR,
                                                 const float* __restrict__ att,
                                                 const float* __restrict__ bias,
                                                 const int* __restrict__ rowptr,
                                                 const int* __restrict__ col,
                                                 float* __restrict__ OUT, int N) {
    int wave = (blockIdx.x * blockDim.x + threadIdx.x) >> 6;
    int lane = threadIdx.x & 63;
    int g = lane >> 4, sub = lane & 15;
    int dst = wave * 4 + g;
    bool vd = dst < N;

    int start = vd ? rowptr[dst] : 0;
    int end   = vd ? rowptr[dst + 1] : 0;

    float xr[8], av[8];
    {
        const float* xrp = &XR[(size_t)(vd ? dst : 0) * 128 + sub * 8];
        *(float4*)&xr[0] = *(const float4*)&xrp[0];
        *(float4*)&xr[4] = *(const float4*)&xrp[4];
        *(float4*)&av[0] = *(const float4*)&att[sub * 8];
        *(float4*)&av[4] = *(const float4*)&att[sub * 8 + 4];
    }

    int deg = end - start;
    int md = max(deg, __shfl_xor(deg, 16));
    md = max(md, __shfl_xor(md, 32));

    float acc[8];
    #pragma unroll
    for (int j = 0; j < 8; ++j) acc[j] = 0.f;
    float s = 0.f;

    for (int i = 0; i < md; i += 2) {
        int pA = start + i, pB = start + i + 1;
        bool vA = pA < end, vB = pB < end;
        int iA = col[vA ? pA : 0];
        int iB = col[vB ? pB : 0];
        uint4 rA = *(const uint4*)&XLh[(size_t)iA * 128 + sub * 8];
        uint4 rB = *(const uint4*)&XLh[(size_t)iB * 128 + sub * 8];
        float xA[8], xB[8];
        {
            const __half2* hA = (const __half2*)&rA;
            const __half2* hB = (const __half2*)&rB;
            #pragma unroll
            for (int q = 0; q < 4; ++q) {
                float2 fA = __half22float2(hA[q]);
                float2 fB = __half22float2(hB[q]);
                xA[2 * q] = fA.x; xA[2 * q + 1] = fA.y;
                xB[2 * q] = fB.x; xB[2 * q + 1] = fB.y;
            }
        }
        float dA = 0.f, dB = 0.f;
        #pragma unroll
        for (int j = 0; j < 8; ++j) {
            float uA = xA[j] + xr[j];
            float uB = xB[j] + xr[j];
            uA = fmaxf(uA, SLOPE * uA);
            uB = fmaxf(uB, SLOPE * uB);
            dA = fmaf(uA, av[j], dA);
            dB = fmaf(uB, av[j], dB);
        }
        float tA = quadsum(dA);
        float tB = quadsum(dB);
        float wA = __expf(fminf(tA, 80.f));
        float wB = __expf(fminf(tB, 80.f));
        wA = vA ? wA : 0.f;
        wB = vB ? wB : 0.f;
        s += wA + wB;
        #pragma unroll
        for (int j = 0; j < 8; ++j) {
            acc[j] = fmaf(wA, xA[j], acc[j]);
            acc[j] = fmaf(wB, xB[j], acc[j]);
        }
    }

    float rs = 1.0f / s;
    if (MEAN) {
        float o[8];
        #pragma unroll
        for (int j = 0; j < 8; ++j) {
            float v = acc[j] * rs;
            v += __shfl_xor(v, 4);
            v += __shfl_xor(v, 8);
            o[j] = fmaxf(fmaf(v, 0.25f, bias[sub * 8 + j]), 0.f);
        }
        if (vd && sub < 4) {
            *(float4*)&OUT[(size_t)dst * 32 + sub * 8]     = *(float4*)&o[0];
            *(float4*)&OUT[(size_t)dst * 32 + sub * 8 + 4] = *(float4*)&o[4];
        }
    } else {
        float o[8];
        #pragma unroll
        for (int j = 0; j < 8; ++j)
            o[j] = fmaxf(fmaf(acc[j], rs, bias[sub * 8 + j]), 0.f);
        if (vd) {
            *(float4*)&OUT[(size_t)dst * 128 + sub * 8]     = *(float4*)&o[0];
            *(float4*)&OUT[(size_t)dst * 128 + sub * 8 + 4] = *(float4*)&o[4];
        }
    }
}

// ---------------- launch ----------------

extern "C" void kernel_launch(void* const* d_in, const int* in_sizes, int n_in,
                              void* d_out, int out_size, void* d_ws, size_t ws_size,
                              hipStream_t stream) {
    const float* x   = (const float*)d_in[0];
    const int*   ei  = (const int*)d_in[1];
    const float* W1l = (const float*)d_in[2];
    const float* W1r = (const float*)d_in[3];
    const float* at1 = (const float*)d_in[4];
    const float* b1  = (const float*)d_in[5];
    const float* W2l = (const float*)d_in[6];
    const float* W2r = (const float*)d_in[7];
    const float* at2 = (const float*)d_in[8];
    const float* b2  = (const float*)d_in[9];
    const float* W3l = (const float*)d_in[10];
    const float* W3r = (const float*)d_in[11];
    const float* at3 = (const float*)d_in[12];
    const float* b3  = (const float*)d_in[13];
    float* out = (float*)d_out;

    int N = in_sizes[0] / 128;
    int E = in_sizes[1] / 2;
    int ET = E + N;
    const int* srcv = ei;
    const int* dstv = ei + E;

    char* p = (char*)d_ws;
    auto alloc = [&](size_t bytes) -> void* {
        void* r = (void*)p;
        p += (bytes + 255) & ~(size_t)255;
        return r;
    };
    __half* XLh = (__half*)alloc((size_t)N * 128 * 2);
    float*  XR  = (float*)alloc((size_t)N * 128 * 4);
    float*  H   = (float*)alloc((size_t)N * 128 * 4);
    int* rowptr = (int*)alloc((size_t)(N + 1) * 4);
    int* deg    = (int*)alloc((size_t)N * 4);
    int* dscan  = (int*)alloc((size_t)N * 4);
    int* cnt    = (int*)alloc((size_t)N * 4);
    int* bsum   = (int*)alloc(1024 * 4);
    int* boff   = (int*)alloc(1024 * 4);
    int* col    = (int*)alloc((size_t)ET * 4);

    // ---- CSR build ----
    k_init<<<(N + 255) / 256, 256, 0, stream>>>(deg, cnt, N);
    k_hist<<<(E + 255) / 256, 256, 0, stream>>>(dstv, deg, E);
    int nb = (N + 1023) / 1024;
    k_scan<<<nb, 256, 0, stream>>>(deg, dscan, bsum, N);
    k_scan<<<1, 256, 0, stream>>>(bsum, boff, nullptr, nb);
    k_scan_add<<<(N + 256) / 256, 256, 0, stream>>>(dscan, boff, rowptr, N, ET);
    k_fill<<<(ET + 255) / 256, 256, 0, stream>>>(srcv, dstv, rowptr, cnt, col, E, N);

    dim3 gg((N + 127) / 128, 2);
    int nfb = (N + 15) / 16;   // 16 dsts per 256-thread block (4 waves x 4 dsts)

    // ---- layer 1 ----
    k_gemm<<<gg, 256, 0, stream>>>(x, W1l, W1r, XLh, XR, N);
    fused_gat<false><<<nfb, 256, 0, stream>>>(XLh, XR, at1, b1, rowptr, col, H, N);
    // ---- layer 2 ----
    k_gemm<<<gg, 256, 0, stream>>>(H, W2l, W2r, XLh, XR, N);
    fused_gat<false><<<nfb, 256, 0, stream>>>(XLh, XR, at2, b2, rowptr, col, H, N);
    // ---- layer 3 ----
    k_gemm<<<gg, 256, 0, stream>>>(H, W3l, W3r, XLh, XR, N);
    fused_gat<true><<<nfb, 256, 0, stream>>>(XLh, XR, at3, b3, rowptr, col, out, N);
}

// Round 5
// 607.036 us; speedup vs baseline: 2.8463x; 1.3105x over previous
//
#include <hip/hip_runtime.h>
#include <hip/hip_bf16.h>
#include <hip/hip_fp16.h>

#define SLOPE 0.2f

typedef __attribute__((ext_vector_type(8))) short bf16x8;
typedef __attribute__((ext_vector_type(4))) float f32x4;

__device__ __forceinline__ unsigned short bf16_rn(float f) {
    unsigned u = __float_as_uint(f);
    return (unsigned short)((u + 0x7FFFu + ((u >> 16) & 1u)) >> 16);
}
__device__ __forceinline__ float bf16_to_f32(unsigned short s) {
    return __uint_as_float(((unsigned)s) << 16);
}

// ---------------- CSR build ----------------

__global__ __launch_bounds__(256) void k_init(int* deg, int* cnt, int n) {
    int i = blockIdx.x * 256 + threadIdx.x;
    if (i < n) { deg[i] = 1; cnt[i] = 0; }   // deg starts at 1: self-loop
}

__global__ __launch_bounds__(256) void k_hist(const int* __restrict__ dstv, int* deg, int E) {
    int i = blockIdx.x * 256 + threadIdx.x;
    if (i < E) atomicAdd(&deg[dstv[i]], 1);
}

__global__ __launch_bounds__(256) void k_scan(const int* __restrict__ in, int* __restrict__ out,
                                              int* bsums, int n) {
    __shared__ int wsum[4];
    int t = threadIdx.x;
    int base = blockIdx.x * 1024 + t * 4;
    int v0 = (base + 0 < n) ? in[base + 0] : 0;
    int v1 = (base + 1 < n) ? in[base + 1] : 0;
    int v2 = (base + 2 < n) ? in[base + 2] : 0;
    int v3 = (base + 3 < n) ? in[base + 3] : 0;
    int tsum = v0 + v1 + v2 + v3;
    int lane = t & 63, wid = t >> 6;
    int x = tsum;
    #pragma unroll
    for (int d = 1; d < 64; d <<= 1) {
        int y = __shfl_up(x, d);
        if (lane >= d) x += y;
    }
    if (lane == 63) wsum[wid] = x;
    __syncthreads();
    if (t == 0) {
        int a = 0;
        for (int w = 0; w < 4; ++w) { int b = wsum[w]; wsum[w] = a; a += b; }
    }
    __syncthreads();
    int excl = x - tsum + wsum[wid];
    if (base + 0 < n) out[base + 0] = excl;
    if (base + 1 < n) out[base + 1] = excl + v0;
    if (base + 2 < n) out[base + 2] = excl + v0 + v1;
    if (base + 3 < n) out[base + 3] = excl + v0 + v1 + v2;
    if (bsums != nullptr && t == 255) bsums[blockIdx.x] = excl + tsum;
}

__global__ __launch_bounds__(256) void k_scan_add(const int* __restrict__ dscan,
                                                  const int* __restrict__ boff,
                                                  int* __restrict__ rowptr, int n, int total) {
    int i = blockIdx.x * 256 + threadIdx.x;
    if (i < n) rowptr[i] = dscan[i] + boff[i >> 10];
    if (i == n) rowptr[n] = total;
}

__global__ __launch_bounds__(256) void k_fill(const int* __restrict__ srcv, const int* __restrict__ dstv,
                                              const int* __restrict__ rowptr, int* cnt, int* col,
                                              int E, int n) {
    int i = blockIdx.x * 256 + threadIdx.x;
    if (i < E) {
        int d = dstv[i];
        int pos = rowptr[d] + atomicAdd(&cnt[d], 1);
        col[pos] = srcv[i];
    } else if (i < E + n) {
        int d = i - E;
        int pos = rowptr[d] + atomicAdd(&cnt[d], 1);
        col[pos] = d;
    }
}

// ---------------- W prep: split fp32 W[k][n] into bf16 hi/lo, transposed [n][k] ----------------

__global__ __launch_bounds__(256) void k_wprep(const float* __restrict__ W,
                                               unsigned short* __restrict__ hiT,
                                               unsigned short* __restrict__ loT) {
    int e = blockIdx.x * 256 + threadIdx.x;   // e = n*128 + k
    int n = e >> 7, k = e & 127;
    float x = W[k * 128 + n];
    unsigned short h = bf16_rn(x);
    hiT[e] = h;
    loT[e] = bf16_rn(x - bf16_to_f32(h));
}

// ---------------- MFMA GEMM (bf16x3 emulation): Y0(half)=X@W0, Y1(float)=X@W1 ----------------
// 128x128 tile/block, 4 waves; wave w owns rows [w*32, w*32+32) x all 128 cols.
// K processed in 4 chunks of 32 (= one mfma_16x16x32 K-step).
// LDS rows stride 80B -> only 2-way bank aliasing on b128 frag reads (free).

#define LDS_A_HI 0
#define LDS_A_LO 10240
#define LDS_B_HI 20480
#define LDS_B_LO 30720

__global__ __launch_bounds__(256) void k_gemm(const float* __restrict__ X,
                                              const unsigned short* __restrict__ Whi,
                                              const unsigned short* __restrict__ Wlo,
                                              __half* __restrict__ Y0, float* __restrict__ Y1,
                                              int M) {
    __shared__ __align__(16) unsigned char lds[40960];
    const unsigned short* whi = Whi + (size_t)blockIdx.y * 16384;
    const unsigned short* wlo = Wlo + (size_t)blockIdx.y * 16384;
    int t = threadIdx.x;
    int row0 = blockIdx.x * 128;
    int lane = t & 63, w = t >> 6;
    int ml = lane & 15, q = lane >> 4;

    // A staging ids: 2 threads per row, each converts 16 floats of the 32-k chunk
    int sm = t >> 1;
    int sh = t & 1;
    int srow = row0 + sm;
    bool svalid = srow < M;

    f32x4 acc[2][8];
    #pragma unroll
    for (int i = 0; i < 2; ++i)
        #pragma unroll
        for (int j = 0; j < 8; ++j) acc[i][j] = (f32x4){0.f, 0.f, 0.f, 0.f};

    for (int ks = 0; ks < 4; ++ks) {
        int k0 = ks * 32;
        // ---- stage A (convert fp32 -> bf16 hi/lo) ----
        {
            float v[16];
            if (svalid) {
                const float* src = X + (size_t)srow * 128 + k0 + sh * 16;
                *(float4*)&v[0]  = *(const float4*)&src[0];
                *(float4*)&v[4]  = *(const float4*)&src[4];
                *(float4*)&v[8]  = *(const float4*)&src[8];
                *(float4*)&v[12] = *(const float4*)&src[12];
            } else {
                #pragma unroll
                for (int j = 0; j < 16; ++j) v[j] = 0.f;
            }
            unsigned hw[8], lw[8];
            #pragma unroll
            for (int j = 0; j < 8; ++j) {
                unsigned short h0 = bf16_rn(v[2 * j]);
                unsigned short h1 = bf16_rn(v[2 * j + 1]);
                unsigned short l0 = bf16_rn(v[2 * j] - bf16_to_f32(h0));
                unsigned short l1 = bf16_rn(v[2 * j + 1] - bf16_to_f32(h1));
                hw[j] = (unsigned)h0 | ((unsigned)h1 << 16);
                lw[j] = (unsigned)l0 | ((unsigned)l1 << 16);
            }
            unsigned char* pa = lds + LDS_A_HI + sm * 80 + sh * 32;
            *(uint4*)(pa)      = *(uint4*)&hw[0];
            *(uint4*)(pa + 16) = *(uint4*)&hw[4];
            unsigned char* pl = lds + LDS_A_LO + sm * 80 + sh * 32;
            *(uint4*)(pl)      = *(uint4*)&lw[0];
            *(uint4*)(pl + 16) = *(uint4*)&lw[4];
        }
        // ---- stage B (straight copy of pre-split, pre-transposed W) ----
        {
            #pragma unroll
            for (int cc = 0; cc < 2; ++cc) {
                int c = t + cc * 256;          // 512 chunks of 16B
                int n = c >> 2, kc = (c & 3) * 8;
                *(uint4*)(lds + LDS_B_HI + n * 80 + (c & 3) * 16) =
                    *(const uint4*)(whi + n * 128 + k0 + kc);
                *(uint4*)(lds + LDS_B_LO + n * 80 + (c & 3) * 16) =
                    *(const uint4*)(wlo + n * 128 + k0 + kc);
            }
        }
        __syncthreads();
        // ---- compute: 48 MFMA / wave / chunk ----
        bf16x8 ah[2], al[2];
        #pragma unroll
        for (int mt = 0; mt < 2; ++mt) {
            int am = w * 32 + mt * 16 + ml;
            ah[mt] = *(const bf16x8*)(lds + LDS_A_HI + am * 80 + q * 16);
            al[mt] = *(const bf16x8*)(lds + LDS_A_LO + am * 80 + q * 16);
        }
        #pragma unroll
        for (int nt = 0; nt < 8; ++nt) {
            int bn = nt * 16 + ml;
            bf16x8 bh = *(const bf16x8*)(lds + LDS_B_HI + bn * 80 + q * 16);
            bf16x8 bl = *(const bf16x8*)(lds + LDS_B_LO + bn * 80 + q * 16);
            #pragma unroll
            for (int mt = 0; mt < 2; ++mt) {
                acc[mt][nt] = __builtin_amdgcn_mfma_f32_16x16x32_bf16(ah[mt], bh, acc[mt][nt], 0, 0, 0);
                acc[mt][nt] = __builtin_amdgcn_mfma_f32_16x16x32_bf16(ah[mt], bl, acc[mt][nt], 0, 0, 0);
                acc[mt][nt] = __builtin_amdgcn_mfma_f32_16x16x32_bf16(al[mt], bh, acc[mt][nt], 0, 0, 0);
            }
        }
        __syncthreads();
    }

    // ---- epilogue: C/D layout col=lane&15, row=(lane>>4)*4+reg ----
    if (blockIdx.y == 0) {
        #pragma unroll
        for (int mt = 0; mt < 2; ++mt) {
            int rbase = row0 + w * 32 + mt * 16 + q * 4;
            #pragma unroll
            for (int r = 0; r < 4; ++r) {
                int row = rbase + r;
                if (row < M) {
                    #pragma unroll
                    for (int nt = 0; nt < 8; ++nt)
                        Y0[(size_t)row * 128 + nt * 16 + ml] = __float2half(acc[mt][nt][r]);
                }
            }
        }
    } else {
        #pragma unroll
        for (int mt = 0; mt < 2; ++mt) {
            int rbase = row0 + w * 32 + mt * 16 + q * 4;
            #pragma unroll
            for (int r = 0; r < 4; ++r) {
                int row = rbase + r;
                if (row < M) {
                    #pragma unroll
                    for (int nt = 0; nt < 8; ++nt)
                        Y1[(size_t)row * 128 + nt * 16 + ml] = acc[mt][nt][r];
                }
            }
        }
    }
}

// ---------------- fused attention: 4 dsts per wave ----------------

__device__ __forceinline__ float quadsum(float t) {
    t += __int_as_float(__builtin_amdgcn_update_dpp(0, __float_as_int(t), 0xB1, 0xf, 0xf, true)); // [1,0,3,2]
    t += __int_as_float(__builtin_amdgcn_update_dpp(0, __float_as_int(t), 0x4E, 0xf, 0xf, true)); // [2,3,0,1]
    return t;
}

template <bool MEAN>
__global__ __launch_bounds__(256) void fused_gat(const __half* __restrict__ XLh,
                                                 const float* __restrict__ XR,
                                                 const float* __restrict__ att,
                                                 const float* __restrict__ bias,
                                                 const int* __restrict__ rowptr,
                                                 const int* __restrict__ col,
                                                 float* __restrict__ OUT, int N) {
    int wave = (blockIdx.x * blockDim.x + threadIdx.x) >> 6;
    int lane = threadIdx.x & 63;
    int g = lane >> 4, sub = lane & 15;
    int dst = wave * 4 + g;
    bool vd = dst < N;

    int start = vd ? rowptr[dst] : 0;
    int end   = vd ? rowptr[dst + 1] : 0;

    float xr[8], av[8];
    {
        const float* xrp = &XR[(size_t)(vd ? dst : 0) * 128 + sub * 8];
        *(float4*)&xr[0] = *(const float4*)&xrp[0];
        *(float4*)&xr[4] = *(const float4*)&xrp[4];
        *(float4*)&av[0] = *(const float4*)&att[sub * 8];
        *(float4*)&av[4] = *(const float4*)&att[sub * 8 + 4];
    }

    int deg = end - start;
    int md = max(deg, __shfl_xor(deg, 16));
    md = max(md, __shfl_xor(md, 32));

    float acc[8];
    #pragma unroll
    for (int j = 0; j < 8; ++j) acc[j] = 0.f;
    float s = 0.f;

    for (int i = 0; i < md; i += 2) {
        int pA = start + i, pB = start + i + 1;
        bool vA = pA < end, vB = pB < end;
        int iA = col[vA ? pA : 0];
        int iB = col[vB ? pB : 0];
        uint4 rA = *(const uint4*)&XLh[(size_t)iA * 128 + sub * 8];
        uint4 rB = *(const uint4*)&XLh[(size_t)iB * 128 + sub * 8];
        float xA[8], xB[8];
        {
            const __half2* hA = (const __half2*)&rA;
            const __half2* hB = (const __half2*)&rB;
            #pragma unroll
            for (int qq = 0; qq < 4; ++qq) {
                float2 fA = __half22float2(hA[qq]);
                float2 fB = __half22float2(hB[qq]);
                xA[2 * qq] = fA.x; xA[2 * qq + 1] = fA.y;
                xB[2 * qq] = fB.x; xB[2 * qq + 1] = fB.y;
            }
        }
        float dA = 0.f, dB = 0.f;
        #pragma unroll
        for (int j = 0; j < 8; ++j) {
            float uA = xA[j] + xr[j];
            float uB = xB[j] + xr[j];
            uA = fmaxf(uA, SLOPE * uA);
            uB = fmaxf(uB, SLOPE * uB);
            dA = fmaf(uA, av[j], dA);
            dB = fmaf(uB, av[j], dB);
        }
        float tA = quadsum(dA);
        float tB = quadsum(dB);
        float wA = __expf(fminf(tA, 80.f));
        float wB = __expf(fminf(tB, 80.f));
        wA = vA ? wA : 0.f;
        wB = vB ? wB : 0.f;
        s += wA + wB;
        #pragma unroll
        for (int j = 0; j < 8; ++j) {
            acc[j] = fmaf(wA, xA[j], acc[j]);
            acc[j] = fmaf(wB, xB[j], acc[j]);
        }
    }

    float rs = 1.0f / s;
    if (MEAN) {
        float o[8];
        #pragma unroll
        for (int j = 0; j < 8; ++j) {
            float v = acc[j] * rs;
            v += __shfl_xor(v, 4);
            v += __shfl_xor(v, 8);
            o[j] = fmaxf(fmaf(v, 0.25f, bias[sub * 8 + j]), 0.f);
        }
        if (vd && sub < 4) {
            *(float4*)&OUT[(size_t)dst * 32 + sub * 8]     = *(float4*)&o[0];
            *(float4*)&OUT[(size_t)dst * 32 + sub * 8 + 4] = *(float4*)&o[4];
        }
    } else {
        float o[8];
        #pragma unroll
        for (int j = 0; j < 8; ++j)
            o[j] = fmaxf(fmaf(acc[j], rs, bias[sub * 8 + j]), 0.f);
        if (vd) {
            *(float4*)&OUT[(size_t)dst * 128 + sub * 8]     = *(float4*)&o[0];
            *(float4*)&OUT[(size_t)dst * 128 + sub * 8 + 4] = *(float4*)&o[4];
        }
    }
}

// ---------------- launch ----------------

extern "C" void kernel_launch(void* const* d_in, const int* in_sizes, int n_in,
                              void* d_out, int out_size, void* d_ws, size_t ws_size,
                              hipStream_t stream) {
    const float* x   = (const float*)d_in[0];
    const int*   ei  = (const int*)d_in[1];
    const float* W1l = (const float*)d_in[2];
    const float* W1r = (const float*)d_in[3];
    const float* at1 = (const float*)d_in[4];
    const float* b1  = (const float*)d_in[5];
    const float* W2l = (const float*)d_in[6];
    const float* W2r = (const float*)d_in[7];
    const float* at2 = (const float*)d_in[8];
    const float* b2  = (const float*)d_in[9];
    const float* W3l = (const float*)d_in[10];
    const float* W3r = (const float*)d_in[11];
    const float* at3 = (const float*)d_in[12];
    const float* b3  = (const float*)d_in[13];
    float* out = (float*)d_out;

    int N = in_sizes[0] / 128;
    int E = in_sizes[1] / 2;
    int ET = E + N;
    const int* srcv = ei;
    const int* dstv = ei + E;

    char* p = (char*)d_ws;
    auto alloc = [&](size_t bytes) -> void* {
        void* r = (void*)p;
        p += (bytes + 255) & ~(size_t)255;
        return r;
    };
    __half* XLh = (__half*)alloc((size_t)N * 128 * 2);
    float*  XR  = (float*)alloc((size_t)N * 128 * 4);
    float*  H   = (float*)alloc((size_t)N * 128 * 4);
    int* rowptr = (int*)alloc((size_t)(N + 1) * 4);
    int* deg    = (int*)alloc((size_t)N * 4);
    int* dscan  = (int*)alloc((size_t)N * 4);
    int* cnt    = (int*)alloc((size_t)N * 4);
    int* bsum   = (int*)alloc(1024 * 4);
    int* boff   = (int*)alloc(1024 * 4);
    int* col    = (int*)alloc((size_t)ET * 4);
    // W tables: per layer [hi: Wl,Wr | lo: Wl,Wr], 65536 ushort per layer
    unsigned short* Wtab = (unsigned short*)alloc((size_t)6 * 65536 * 2);

    // ---- W prep (graph-safe, every call) ----
    const float* Ws[6] = { W1l, W1r, W2l, W2r, W3l, W3r };
    for (int j = 0; j < 6; ++j) {
        int L = j >> 1, side = j & 1;
        unsigned short* hiT = Wtab + (size_t)L * 65536 + side * 16384;
        unsigned short* loT = hiT + 32768;
        k_wprep<<<64, 256, 0, stream>>>(Ws[j], hiT, loT);
    }

    // ---- CSR build ----
    k_init<<<(N + 255) / 256, 256, 0, stream>>>(deg, cnt, N);
    k_hist<<<(E + 255) / 256, 256, 0, stream>>>(dstv, deg, E);
    int nb = (N + 1023) / 1024;
    k_scan<<<nb, 256, 0, stream>>>(deg, dscan, bsum, N);
    k_scan<<<1, 256, 0, stream>>>(bsum, boff, nullptr, nb);
    k_scan_add<<<(N + 256) / 256, 256, 0, stream>>>(dscan, boff, rowptr, N, ET);
    k_fill<<<(ET + 255) / 256, 256, 0, stream>>>(srcv, dstv, rowptr, cnt, col, E, N);

    dim3 gg((N + 127) / 128, 2);
    int nfb = (N + 15) / 16;

    // ---- layer 1 ----
    k_gemm<<<gg, 256, 0, stream>>>(x, Wtab + 0 * 65536, Wtab + 0 * 65536 + 32768, XLh, XR, N);
    fused_gat<false><<<nfb, 256, 0, stream>>>(XLh, XR, at1, b1, rowptr, col, H, N);
    // ---- layer 2 ----
    k_gemm<<<gg, 256, 0, stream>>>(H, Wtab + 1 * 65536, Wtab + 1 * 65536 + 32768, XLh, XR, N);
    fused_gat<false><<<nfb, 256, 0, stream>>>(XLh, XR, at2, b2, rowptr, col, H, N);
    // ---- layer 3 ----
    k_gemm<<<gg, 256, 0, stream>>>(H, Wtab + 2 * 65536, Wtab + 2 * 65536 + 32768, XLh, XR, N);
    fused_gat<true><<<nfb, 256, 0, stream>>>(XLh, XR, at3, b3, rowptr, col, out, N);
}